// Round 6
// baseline (271.645 us; speedup 1.0000x reference)
//
#include <hip/hip_runtime.h>
#include <math.h>

#define NN 100000
#define NE 1600000
#define IC 128
#define OC 64
#define NEG_SLOPE 0.2f
#define EPS_F 1e-10f

typedef short bf16x8 __attribute__((ext_vector_type(8)));
typedef float f32x4 __attribute__((ext_vector_type(4)));

__device__ __forceinline__ unsigned short f2bf(float f) {  // RNE
    unsigned u = __float_as_uint(f);
    u += 0x7fff + ((u >> 16) & 1);
    return (unsigned short)(u >> 16);
}

// ---------------- h = x @ W^T via bf16 MFMA + fused e_l/e_r ----------------
// Block: 256 thr = 4 waves, 64 nodes x 64 oc. Wave w: nodes w*16..+15, all 64 oc
// (4 oc-tiles of 16). K=128 -> 4 mfma_16x16x32 per tile. LDS rows padded to
// 136 bf16 (=17 x 16B chunks, gcd(17,8)=1 -> worst 2-way b128 conflicts = free).
__global__ __launch_bounds__(256) void linear_kernel(
    const float* __restrict__ x, const float* __restrict__ W,
    const float* __restrict__ a_l, const float* __restrict__ a_r,
    unsigned short* __restrict__ h_bf, float* __restrict__ e_l,
    float* __restrict__ e_r)
{
    __shared__ unsigned short lds[128 * 136];   // rows 0-63: x tile, 64-127: W
    const int tid = threadIdx.x;
    const int n0 = blockIdx.x * 64;

    // stage x tile (fp32 -> bf16)
#pragma unroll
    for (int it = 0; it < 8; it++) {
        int i = it * 256 + tid;          // float4 index, 2048 total
        int r = i >> 5, c4 = i & 31;
        int n = n0 + r;
        float4 v = make_float4(0.f, 0.f, 0.f, 0.f);
        if (n < NN) v = *(const float4*)&x[(size_t)n * 128 + (c4 << 2)];
        ushort4 b;
        b.x = f2bf(v.x); b.y = f2bf(v.y); b.z = f2bf(v.z); b.w = f2bf(v.w);
        *(ushort4*)&lds[r * 136 + (c4 << 2)] = b;
    }
    // stage W (fp32 -> bf16)
#pragma unroll
    for (int it = 0; it < 8; it++) {
        int i = it * 256 + tid;
        int r = i >> 5, c4 = i & 31;
        float4 v = *(const float4*)&W[r * 128 + (c4 << 2)];
        ushort4 b;
        b.x = f2bf(v.x); b.y = f2bf(v.y); b.z = f2bf(v.z); b.w = f2bf(v.w);
        *(ushort4*)&lds[(64 + r) * 136 + (c4 << 2)] = b;
    }
    __syncthreads();

    const int wv = tid >> 6;
    const int lane = tid & 63;
    const int q = lane >> 4;      // quad: k-group for A/B, row-group for C/D
    const int c = lane & 15;      // A: node row; B: oc row; C/D: oc col

    f32x4 acc[4];
#pragma unroll
    for (int t = 0; t < 4; t++) acc[t] = (f32x4){0.f, 0.f, 0.f, 0.f};

    const unsigned short* xrow = &lds[(wv * 16 + c) * 136];
    const unsigned short* wrow = &lds[(64 + c) * 136];

#pragma unroll
    for (int kk = 0; kk < 4; kk++) {
        int ko = kk * 32 + q * 8;
        bf16x8 a = *(const bf16x8*)&xrow[ko];
#pragma unroll
        for (int t = 0; t < 4; t++) {
            bf16x8 b = *(const bf16x8*)&wrow[t * 16 * 136 + ko];
            acc[t] = __builtin_amdgcn_mfma_f32_16x16x32_bf16(a, b, acc[t], 0, 0, 0);
        }
    }

    // h store: node m = n0 + wv*16 + q*4 + r, oc = t*16 + c
#pragma unroll
    for (int r = 0; r < 4; r++) {
        int m = n0 + wv * 16 + q * 4 + r;
        if (m < NN) {
#pragma unroll
            for (int t = 0; t < 4; t++)
                h_bf[(size_t)m * OC + t * 16 + c] = f2bf(acc[t][r]);
        }
    }

    // fused e_l/e_r: dot over oc (this lane holds oc = t*16+c), reduce 16 oc-lanes
    float al[4], ar[4];
#pragma unroll
    for (int t = 0; t < 4; t++) { al[t] = a_l[t * 16 + c]; ar[t] = a_r[t * 16 + c]; }
    float pl[4], pr[4];
#pragma unroll
    for (int r = 0; r < 4; r++) {
        pl[r] = al[0] * acc[0][r] + al[1] * acc[1][r] + al[2] * acc[2][r] + al[3] * acc[3][r];
        pr[r] = ar[0] * acc[0][r] + ar[1] * acc[1][r] + ar[2] * acc[2][r] + ar[3] * acc[3][r];
    }
#pragma unroll
    for (int m = 1; m < 16; m <<= 1) {
#pragma unroll
        for (int r = 0; r < 4; r++) {
            pl[r] += __shfl_xor(pl[r], m);
            pr[r] += __shfl_xor(pr[r], m);
        }
    }
    if (c == 0) {
#pragma unroll
        for (int r = 0; r < 4; r++) {
            int m = n0 + wv * 16 + q * 4 + r;
            if (m < NN) { e_l[m] = pl[r]; e_r[m] = pr[r]; }
        }
    }
}

// ---------------- degree + rank (atomic return = rank within dst segment) ----------------
__global__ __launch_bounds__(256) void degrank_kernel(
    const int* __restrict__ dst, int* __restrict__ deg, int* __restrict__ rank)
{
    int g = blockIdx.x * 256 + threadIdx.x;
    if (g >= NE / 4) return;
    int4 d = ((const int4*)dst)[g];
    int4 r;
    r.x = atomicAdd(&deg[d.x], 1);
    r.y = atomicAdd(&deg[d.y], 1);
    r.z = atomicAdd(&deg[d.z], 1);
    r.w = atomicAdd(&deg[d.w], 1);
    ((int4*)rank)[g] = r;
}

// ---------------- wave-shuffle block scan ----------------
__global__ __launch_bounds__(1024) void scan_block_kernel(
    const int* __restrict__ deg, int* __restrict__ offsets,
    int* __restrict__ bsums)
{
    __shared__ int wsum[16];
    const int t = threadIdx.x;
    const int lane = t & 63, wv = t >> 6;
    const int i = blockIdx.x * 1024 + t;
    int v = (i < NN) ? deg[i] : 0;
    int incl = v;
#pragma unroll
    for (int off = 1; off < 64; off <<= 1) {
        int u = __shfl_up(incl, off);
        if (lane >= off) incl += u;
    }
    if (lane == 63) wsum[wv] = incl;
    __syncthreads();
    if (wv == 0 && lane < 16) {
        int s = wsum[lane];
        int si = s;
#pragma unroll
        for (int off = 1; off < 16; off <<= 1) {
            int u = __shfl_up(si, off);
            if (lane >= off) si += u;
        }
        wsum[lane] = si - s;
    }
    __syncthreads();
    int excl = incl - v + wsum[wv];
    if (i < NN) offsets[i] = excl;
    if (t == 1023) bsums[blockIdx.x] = excl + v;
}

__global__ __launch_bounds__(128) void scan_bsums_kernel(
    int* __restrict__ bsums, int* __restrict__ offsets)
{
    __shared__ int s[128];
    const int t = threadIdx.x;
    const int NB = (NN + 1023) / 1024;
    int v = (t < NB) ? bsums[t] : 0;
    s[t] = v;
    __syncthreads();
    for (int off = 1; off < 128; off <<= 1) {
        int u = (t >= off) ? s[t - off] : 0;
        __syncthreads();
        s[t] += u;
        __syncthreads();
    }
    if (t < NB) bsums[t] = s[t] - v;
    if (t == NB - 1) offsets[NN] = s[t];
}

__global__ __launch_bounds__(1024) void scan_add_kernel(
    int* __restrict__ offsets, const int* __restrict__ bsums)
{
    int i = blockIdx.x * 1024 + threadIdx.x;
    if (i < NN) offsets[i] += bsums[blockIdx.x];
}

// ---------------- scatter: src index only (4B/edge), no atomics ----------------
__global__ __launch_bounds__(256) void scatter_kernel(
    const int* __restrict__ src, const int* __restrict__ dst,
    const int* __restrict__ rank, const int* __restrict__ offsets,
    int* __restrict__ sorted_src)
{
    int g = blockIdx.x * 256 + threadIdx.x;
    if (g >= NE / 4) return;
    int4 d4 = ((const int4*)dst)[g];
    int4 s4 = ((const int4*)src)[g];
    int4 r4 = ((const int4*)rank)[g];
    sorted_src[offsets[d4.x] + r4.x] = s4.x;
    sorted_src[offsets[d4.y] + r4.y] = s4.y;
    sorted_src[offsets[d4.z] + r4.z] = s4.z;
    sorted_src[offsets[d4.w] + r4.w] = s4.w;
}

// ---------------- softmax + aggregate: w computed on the fly ----------------
// one wave per dst node; 8 lanes per edge, each lane gathers 16B (8 bf16 ch).
__global__ __launch_bounds__(256) void aggregate_kernel(
    const unsigned short* __restrict__ h_bf, const int* __restrict__ offsets,
    const int* __restrict__ sorted_src, const float* __restrict__ e_l,
    const float* __restrict__ e_r, const float* __restrict__ bias,
    float* __restrict__ out)
{
    const int node = blockIdx.x * 4 + (threadIdx.x >> 6);
    const int lane = threadIdx.x & 63;
    if (node >= NN) return;
    const int start = offsets[node];
    const int end = offsets[node + 1];
    const int grp = lane >> 3;        // which of 8 edges in the group
    const int ch = (lane & 7) * 8;    // channel base (8 channels per lane)
    const float el = e_l[node];

    float acc[8] = {0.f, 0.f, 0.f, 0.f, 0.f, 0.f, 0.f, 0.f};
    float wsum = 0.f;

#pragma unroll 2
    for (int j = start; j < end; j += 8) {
        int eidx = j + grp;
        int ej = (eidx < end) ? eidx : end - 1;   // clamp: no OOB
        int s = sorted_src[ej];
        float a = el + e_r[s];                     // e_r: 400KB, L2-resident gather
        a = (a > 0.f) ? a : NEG_SLOPE * a;
        float w = (eidx < end) ? __expf(a) : 0.f;  // |a| small: fp32-safe, no max shift
        uint4 qv = *(const uint4*)&h_bf[(size_t)s * OC + ch];
        wsum += w;
        acc[0] += w * __uint_as_float(qv.x << 16);
        acc[1] += w * __uint_as_float(qv.x & 0xffff0000u);
        acc[2] += w * __uint_as_float(qv.y << 16);
        acc[3] += w * __uint_as_float(qv.y & 0xffff0000u);
        acc[4] += w * __uint_as_float(qv.z << 16);
        acc[5] += w * __uint_as_float(qv.z & 0xffff0000u);
        acc[6] += w * __uint_as_float(qv.w << 16);
        acc[7] += w * __uint_as_float(qv.w & 0xffff0000u);
    }

#pragma unroll
    for (int m = 8; m <= 32; m <<= 1) {
#pragma unroll
        for (int k = 0; k < 8; k++) acc[k] += __shfl_xor(acc[k], m);
        wsum += __shfl_xor(wsum, m);
    }

    if (lane < 8) {
        float inv = 1.f / (wsum + EPS_F);
        float4 b0 = *(const float4*)&bias[lane * 8];
        float4 b1 = *(const float4*)&bias[lane * 8 + 4];
        float4 o0 = make_float4(acc[0] * inv + b0.x, acc[1] * inv + b0.y,
                                acc[2] * inv + b0.z, acc[3] * inv + b0.w);
        float4 o1 = make_float4(acc[4] * inv + b1.x, acc[5] * inv + b1.y,
                                acc[6] * inv + b1.z, acc[7] * inv + b1.w);
        *(float4*)&out[(size_t)node * OC + lane * 8] = o0;
        *(float4*)&out[(size_t)node * OC + lane * 8 + 4] = o1;
    }
}

extern "C" void kernel_launch(void* const* d_in, const int* in_sizes, int n_in,
                              void* d_out, int out_size, void* d_ws, size_t ws_size,
                              hipStream_t stream)
{
    const float* x = (const float*)d_in[0];
    const int* edge_index = (const int*)d_in[1];
    const float* W = (const float*)d_in[2];
    const float* a_l = (const float*)d_in[3];
    const float* a_r = (const float*)d_in[4];
    const float* bias = (const float*)d_in[5];
    float* out = (float*)d_out;

    const int* src = edge_index;       // row 0
    const int* dst = edge_index + NE;  // row 1

    // workspace layout (16B-aligned chunks)
    char* w = (char*)d_ws;
    unsigned short* h_bf = (unsigned short*)w;          // NN*OC bf16 = 12.8 MB
    size_t off = (size_t)NN * OC * 2;
    float* e_l = (float*)(w + off); off += (size_t)NN * 4;
    float* e_r = (float*)(w + off); off += (size_t)NN * 4;
    int* deg = (int*)(w + off);     off += (size_t)NN * 4;
    int* offsets = (int*)(w + off); off += (size_t)(NN + 4) * 4;
    int* bsums = (int*)(w + off);   off += 128 * 4;
    int* rank = (int*)(w + off);    off += (size_t)NE * 4;
    int* sorted_src = (int*)(w + off); off += (size_t)NE * 4;

    hipMemsetAsync(deg, 0, (size_t)NN * 4, stream);

    linear_kernel<<<(NN + 63) / 64, 256, 0, stream>>>(x, W, a_l, a_r, h_bf, e_l, e_r);
    degrank_kernel<<<(NE / 4 + 255) / 256, 256, 0, stream>>>(dst, deg, rank);
    scan_block_kernel<<<(NN + 1023) / 1024, 1024, 0, stream>>>(deg, offsets, bsums);
    scan_bsums_kernel<<<1, 128, 0, stream>>>(bsums, offsets);
    scan_add_kernel<<<(NN + 1023) / 1024, 1024, 0, stream>>>(offsets, bsums);
    scatter_kernel<<<(NE / 4 + 255) / 256, 256, 0, stream>>>(src, dst, rank, offsets, sorted_src);
    aggregate_kernel<<<(NN + 3) / 4, 256, 0, stream>>>(h_bf, offsets, sorted_src,
                                                       e_l, e_r, bias, out);
}

// Round 8
// 202.712 us; speedup vs baseline: 1.3401x; 1.3401x over previous
//
#include <hip/hip_runtime.h>
#include <math.h>

#define NN 100000
#define NE 1600000
#define IC 128
#define OC 64
#define NEG_SLOPE 0.2f
#define EPS_F 1e-10f

// CSR-build geometry: NN == NSLICE*SN, NE/4 == EB*QPB, scan length NSLICE*EB == NN
#define NSLICE 200   // dst slices
#define SN 500       // nodes per slice
#define EB 500       // edge blocks for hist/bucket kernels
#define QPB 800      // int4 quads per edge block (3200 edges); 500*800 == 400000 == NE/4
#define CAP 12000    // per-slice edge capacity in K4 LDS (mean 8000, sigma ~89)

typedef short bf16x8 __attribute__((ext_vector_type(8)));
typedef float f32x4 __attribute__((ext_vector_type(4)));

__device__ __forceinline__ unsigned short f2bf(float f) {  // RNE
    unsigned u = __float_as_uint(f);
    u += 0x7fff + ((u >> 16) & 1);
    return (unsigned short)(u >> 16);
}

// ---------------- h = x @ W^T via bf16 MFMA + fused e_l/e_r ----------------
__global__ __launch_bounds__(256) void linear_kernel(
    const float* __restrict__ x, const float* __restrict__ W,
    const float* __restrict__ a_l, const float* __restrict__ a_r,
    unsigned short* __restrict__ h_bf, float* __restrict__ e_l,
    float* __restrict__ e_r)
{
    __shared__ unsigned short lds[128 * 136];   // rows 0-63: x tile, 64-127: W
    const int tid = threadIdx.x;
    const int n0 = blockIdx.x * 64;

#pragma unroll
    for (int it = 0; it < 8; it++) {
        int i = it * 256 + tid;
        int r = i >> 5, c4 = i & 31;
        int n = n0 + r;
        float4 v = make_float4(0.f, 0.f, 0.f, 0.f);
        if (n < NN) v = *(const float4*)&x[(size_t)n * 128 + (c4 << 2)];
        ushort4 b;
        b.x = f2bf(v.x); b.y = f2bf(v.y); b.z = f2bf(v.z); b.w = f2bf(v.w);
        *(ushort4*)&lds[r * 136 + (c4 << 2)] = b;
    }
#pragma unroll
    for (int it = 0; it < 8; it++) {
        int i = it * 256 + tid;
        int r = i >> 5, c4 = i & 31;
        float4 v = *(const float4*)&W[r * 128 + (c4 << 2)];
        ushort4 b;
        b.x = f2bf(v.x); b.y = f2bf(v.y); b.z = f2bf(v.z); b.w = f2bf(v.w);
        *(ushort4*)&lds[(64 + r) * 136 + (c4 << 2)] = b;
    }
    __syncthreads();

    const int wv = tid >> 6;
    const int lane = tid & 63;
    const int q = lane >> 4;
    const int c = lane & 15;

    f32x4 acc[4];
#pragma unroll
    for (int t = 0; t < 4; t++) acc[t] = (f32x4){0.f, 0.f, 0.f, 0.f};

    const unsigned short* xrow = &lds[(wv * 16 + c) * 136];
    const unsigned short* wrow = &lds[(64 + c) * 136];

#pragma unroll
    for (int kk = 0; kk < 4; kk++) {
        int ko = kk * 32 + q * 8;
        bf16x8 a = *(const bf16x8*)&xrow[ko];
#pragma unroll
        for (int t = 0; t < 4; t++) {
            bf16x8 b = *(const bf16x8*)&wrow[t * 16 * 136 + ko];
            acc[t] = __builtin_amdgcn_mfma_f32_16x16x32_bf16(a, b, acc[t], 0, 0, 0);
        }
    }

#pragma unroll
    for (int r = 0; r < 4; r++) {
        int m = n0 + wv * 16 + q * 4 + r;
        if (m < NN) {
#pragma unroll
            for (int t = 0; t < 4; t++)
                h_bf[(size_t)m * OC + t * 16 + c] = f2bf(acc[t][r]);
        }
    }

    float al[4], ar[4];
#pragma unroll
    for (int t = 0; t < 4; t++) { al[t] = a_l[t * 16 + c]; ar[t] = a_r[t * 16 + c]; }
    float pl[4], pr[4];
#pragma unroll
    for (int r = 0; r < 4; r++) {
        pl[r] = al[0] * acc[0][r] + al[1] * acc[1][r] + al[2] * acc[2][r] + al[3] * acc[3][r];
        pr[r] = ar[0] * acc[0][r] + ar[1] * acc[1][r] + ar[2] * acc[2][r] + ar[3] * acc[3][r];
    }
#pragma unroll
    for (int m = 1; m < 16; m <<= 1) {
#pragma unroll
        for (int r = 0; r < 4; r++) {
            pl[r] += __shfl_xor(pl[r], m);
            pr[r] += __shfl_xor(pr[r], m);
        }
    }
    if (c == 0) {
#pragma unroll
        for (int r = 0; r < 4; r++) {
            int m = n0 + wv * 16 + q * 4 + r;
            if (m < NN) { e_l[m] = pl[r]; e_r[m] = pr[r]; }
        }
    }
}

// ---------------- K1: per-block LDS histogram over dst slices ----------------
__global__ __launch_bounds__(256) void hist_kernel(
    const int* __restrict__ dst, int* __restrict__ H)
{
    __shared__ int hist[NSLICE];
    const int t = threadIdx.x, b = blockIdx.x;
    if (t < NSLICE) hist[t] = 0;
    __syncthreads();
    for (int qi = t; qi < QPB; qi += 256) {
        int4 d = ((const int4*)dst)[b * QPB + qi];
        atomicAdd(&hist[d.x / SN], 1);
        atomicAdd(&hist[d.y / SN], 1);
        atomicAdd(&hist[d.z / SN], 1);
        atomicAdd(&hist[d.w / SN], 1);
    }
    __syncthreads();
    if (t < NSLICE) H[t * EB + b] = hist[t];   // slice-major, block-minor
}

// ---------------- K2: 3-phase scan over H (length NSLICE*EB == NN) ----------------
__global__ __launch_bounds__(1024) void scan_block_kernel(
    const int* __restrict__ deg, int* __restrict__ offsets,
    int* __restrict__ bsums)
{
    __shared__ int wsum[16];
    const int t = threadIdx.x;
    const int lane = t & 63, wv = t >> 6;
    const int i = blockIdx.x * 1024 + t;
    int v = (i < NN) ? deg[i] : 0;
    int incl = v;
#pragma unroll
    for (int off = 1; off < 64; off <<= 1) {
        int u = __shfl_up(incl, off);
        if (lane >= off) incl += u;
    }
    if (lane == 63) wsum[wv] = incl;
    __syncthreads();
    if (wv == 0 && lane < 16) {
        int s = wsum[lane];
        int si = s;
#pragma unroll
        for (int off = 1; off < 16; off <<= 1) {
            int u = __shfl_up(si, off);
            if (lane >= off) si += u;
        }
        wsum[lane] = si - s;
    }
    __syncthreads();
    int excl = incl - v + wsum[wv];
    if (i < NN) offsets[i] = excl;
    if (t == 1023) bsums[blockIdx.x] = excl + v;
}

__global__ __launch_bounds__(128) void scan_bsums_kernel(
    int* __restrict__ bsums, int* __restrict__ offsets)
{
    __shared__ int s[128];
    const int t = threadIdx.x;
    const int NB = (NN + 1023) / 1024;
    int v = (t < NB) ? bsums[t] : 0;
    s[t] = v;
    __syncthreads();
    for (int off = 1; off < 128; off <<= 1) {
        int u = (t >= off) ? s[t - off] : 0;
        __syncthreads();
        s[t] += u;
        __syncthreads();
    }
    if (t < NB) bsums[t] = s[t] - v;
    if (t == NB - 1) offsets[NN] = s[t];
}

__global__ __launch_bounds__(1024) void scan_add_kernel(
    int* __restrict__ offsets, const int* __restrict__ bsums)
{
    int i = blockIdx.x * 1024 + threadIdx.x;
    if (i < NN) offsets[i] += bsums[blockIdx.x];
}

// ---------------- K3: bucket edges by slice (LDS cursors, packed 4B payload) ----------------
__global__ __launch_bounds__(256) void bucket_kernel(
    const int* __restrict__ src, const int* __restrict__ dst,
    const int* __restrict__ O_flat, int* __restrict__ bucketed)
{
    __shared__ int cur[NSLICE];
    const int t = threadIdx.x, b = blockIdx.x;
    if (t < NSLICE) cur[t] = O_flat[t * EB + b];
    __syncthreads();
    for (int qi = t; qi < QPB; qi += 256) {
        int4 d4 = ((const int4*)dst)[b * QPB + qi];
        int4 s4 = ((const int4*)src)[b * QPB + qi];
        int dd[4] = {d4.x, d4.y, d4.z, d4.w};
        int ss[4] = {s4.x, s4.y, s4.z, s4.w};
#pragma unroll
        for (int k = 0; k < 4; k++) {
            int sl = dd[k] / SN;
            int pos = atomicAdd(&cur[sl], 1);
            bucketed[pos] = ((dd[k] - sl * SN) << 17) | ss[k];   // dloc<512, src<2^17
        }
    }
}

// ---------------- K4: per-slice fine counting sort in LDS ----------------
__global__ __launch_bounds__(1024) void fine_sort_kernel(
    const int* __restrict__ bucketed, const int* __restrict__ O_flat,
    int* __restrict__ sorted_src, int* __restrict__ offsets_out)
{
    __shared__ int ebuf[CAP];
    __shared__ int hist[SN];
    __shared__ int wsums[8];
    const int s = blockIdx.x, t = threadIdx.x;
    const int B0 = O_flat[s * EB];
    int cnt = O_flat[(s + 1) * EB] - B0;   // s==NSLICE-1 -> O_flat[NN] == NE
    if (cnt > CAP) cnt = CAP;              // statistically unreachable

    for (int i = t; i < cnt; i += 1024) ebuf[i] = bucketed[B0 + i];
    for (int i = t; i < SN; i += 1024) hist[i] = 0;
    __syncthreads();
    for (int i = t; i < cnt; i += 1024) atomicAdd(&hist[ebuf[i] >> 17], 1);
    __syncthreads();

    // exclusive scan of hist[0..SN) using waves 0..7
    const int lane = t & 63, w = t >> 6;
    int v = (t < SN) ? hist[t] : 0;
    int incl = v;
#pragma unroll
    for (int o = 1; o < 64; o <<= 1) {
        int u = __shfl_up(incl, o);
        if (lane >= o) incl += u;
    }
    if (w < 8 && lane == 63) wsums[w] = incl;
    __syncthreads();
    if (t == 0) {
        int run = 0;
#pragma unroll
        for (int k = 0; k < 8; k++) { int x = wsums[k]; wsums[k] = run; run += x; }
    }
    __syncthreads();
    int excl = incl - v + ((w < 8) ? wsums[w] : 0);

    if (t < SN) offsets_out[s * SN + t] = B0 + excl;
    __syncthreads();
    if (t < SN) hist[t] = excl;            // reuse as cursor
    __syncthreads();
    for (int i = t; i < cnt; i += 1024) {
        int p = ebuf[i];
        int pos = atomicAdd(&hist[p >> 17], 1);
        sorted_src[B0 + pos] = p & 0x1FFFF;   // dense 32KB window -> L2-combined
    }
    if (s == 0 && t == 0) offsets_out[NN] = NE;
}

// ---------------- softmax + aggregate: w computed on the fly ----------------
__global__ __launch_bounds__(256) void aggregate_kernel(
    const unsigned short* __restrict__ h_bf, const int* __restrict__ offsets,
    const int* __restrict__ sorted_src, const float* __restrict__ e_l,
    const float* __restrict__ e_r, const float* __restrict__ bias,
    float* __restrict__ out)
{
    const int node = blockIdx.x * 4 + (threadIdx.x >> 6);
    const int lane = threadIdx.x & 63;
    if (node >= NN) return;
    const int start = offsets[node];
    const int end = offsets[node + 1];
    const int grp = lane >> 3;
    const int ch = (lane & 7) * 8;
    const float el = e_l[node];

    float acc[8] = {0.f, 0.f, 0.f, 0.f, 0.f, 0.f, 0.f, 0.f};
    float wsum = 0.f;

#pragma unroll 2
    for (int j = start; j < end; j += 8) {
        int eidx = j + grp;
        int ej = (eidx < end) ? eidx : end - 1;
        int s = sorted_src[ej];
        float a = el + e_r[s];
        a = (a > 0.f) ? a : NEG_SLOPE * a;
        float w = (eidx < end) ? __expf(a) : 0.f;
        uint4 qv = *(const uint4*)&h_bf[(size_t)s * OC + ch];
        wsum += w;
        acc[0] += w * __uint_as_float(qv.x << 16);
        acc[1] += w * __uint_as_float(qv.x & 0xffff0000u);
        acc[2] += w * __uint_as_float(qv.y << 16);
        acc[3] += w * __uint_as_float(qv.y & 0xffff0000u);
        acc[4] += w * __uint_as_float(qv.z << 16);
        acc[5] += w * __uint_as_float(qv.z & 0xffff0000u);
        acc[6] += w * __uint_as_float(qv.w << 16);
        acc[7] += w * __uint_as_float(qv.w & 0xffff0000u);
    }

#pragma unroll
    for (int m = 8; m <= 32; m <<= 1) {
#pragma unroll
        for (int k = 0; k < 8; k++) acc[k] += __shfl_xor(acc[k], m);
        wsum += __shfl_xor(wsum, m);
    }

    if (lane < 8) {
        float inv = 1.f / (wsum + EPS_F);
        float4 b0 = *(const float4*)&bias[lane * 8];
        float4 b1 = *(const float4*)&bias[lane * 8 + 4];
        float4 o0 = make_float4(acc[0] * inv + b0.x, acc[1] * inv + b0.y,
                                acc[2] * inv + b0.z, acc[3] * inv + b0.w);
        float4 o1 = make_float4(acc[4] * inv + b1.x, acc[5] * inv + b1.y,
                                acc[6] * inv + b1.z, acc[7] * inv + b1.w);
        *(float4*)&out[(size_t)node * OC + lane * 8] = o0;
        *(float4*)&out[(size_t)node * OC + lane * 8 + 4] = o1;
    }
}

extern "C" void kernel_launch(void* const* d_in, const int* in_sizes, int n_in,
                              void* d_out, int out_size, void* d_ws, size_t ws_size,
                              hipStream_t stream)
{
    const float* x = (const float*)d_in[0];
    const int* edge_index = (const int*)d_in[1];
    const float* W = (const float*)d_in[2];
    const float* a_l = (const float*)d_in[3];
    const float* a_r = (const float*)d_in[4];
    const float* bias = (const float*)d_in[5];
    float* out = (float*)d_out;

    const int* src = edge_index;       // row 0
    const int* dst = edge_index + NE;  // row 1

    // workspace layout (16B-aligned chunks); everything fully overwritten each call
    char* w = (char*)d_ws;
    unsigned short* h_bf = (unsigned short*)w;          // 12.8 MB
    size_t off = (size_t)NN * OC * 2;
    float* e_l = (float*)(w + off); off += (size_t)NN * 4;
    float* e_r = (float*)(w + off); off += (size_t)NN * 4;
    int* H = (int*)(w + off);       off += (size_t)NN * 4;          // NSLICE*EB == NN
    int* O_flat = (int*)(w + off);  off += (size_t)(NN + 4) * 4;
    int* bsums = (int*)(w + off);   off += 128 * 4;
    int* offsets = (int*)(w + off); off += (size_t)(NN + 4) * 4;
    int* bucketed = (int*)(w + off); off += (size_t)NE * 4;
    int* sorted_src = (int*)(w + off); off += (size_t)NE * 4;

    linear_kernel<<<(NN + 63) / 64, 256, 0, stream>>>(x, W, a_l, a_r, h_bf, e_l, e_r);
    hist_kernel<<<EB, 256, 0, stream>>>(dst, H);
    scan_block_kernel<<<(NN + 1023) / 1024, 1024, 0, stream>>>(H, O_flat, bsums);
    scan_bsums_kernel<<<1, 128, 0, stream>>>(bsums, O_flat);
    scan_add_kernel<<<(NN + 1023) / 1024, 1024, 0, stream>>>(O_flat, bsums);
    bucket_kernel<<<EB, 256, 0, stream>>>(src, dst, O_flat, bucketed);
    fine_sort_kernel<<<NSLICE, 1024, 0, stream>>>(bucketed, O_flat, sorted_src, offsets);
    aggregate_kernel<<<(NN + 3) / 4, 256, 0, stream>>>(h_bf, offsets, sorted_src,
                                                       e_l, e_r, bias, out);
}

// Round 9
// 199.090 us; speedup vs baseline: 1.3644x; 1.0182x over previous
//
#include <hip/hip_runtime.h>
#include <math.h>

#define NN 100000
#define NE 1600000
#define IC 128
#define OC 64
#define NEG_SLOPE 0.2f
#define EPS_F 1e-10f

// CSR-build geometry: NN == NSLICE*SN, NE/4 == EB*QPB, scan length NSLICE*EB == NN
#define NSLICE 200   // dst slices
#define SN 500       // nodes per slice
#define EB 500       // edge blocks for hist/bucket kernels
#define QPB 800      // int4 quads per edge block (3200 edges); 500*800 == 400000 == NE/4
#define CAP 12000    // per-slice edge capacity in K4 LDS (mean 8000, sigma ~89)

typedef short bf16x8 __attribute__((ext_vector_type(8)));
typedef float f32x4 __attribute__((ext_vector_type(4)));

__device__ __forceinline__ unsigned short f2bf(float f) {  // RNE
    unsigned u = __float_as_uint(f);
    u += 0x7fff + ((u >> 16) & 1);
    return (unsigned short)(u >> 16);
}

// ---------------- h = x @ W^T via bf16 MFMA + fused e_l/e_r ----------------
__global__ __launch_bounds__(256) void linear_kernel(
    const float* __restrict__ x, const float* __restrict__ W,
    const float* __restrict__ a_l, const float* __restrict__ a_r,
    unsigned short* __restrict__ h_bf, float* __restrict__ e_l,
    float* __restrict__ e_r)
{
    __shared__ unsigned short lds[128 * 136];   // rows 0-63: x tile, 64-127: W
    const int tid = threadIdx.x;
    const int n0 = blockIdx.x * 64;

#pragma unroll
    for (int it = 0; it < 8; it++) {
        int i = it * 256 + tid;
        int r = i >> 5, c4 = i & 31;
        int n = n0 + r;
        float4 v = make_float4(0.f, 0.f, 0.f, 0.f);
        if (n < NN) v = *(const float4*)&x[(size_t)n * 128 + (c4 << 2)];
        ushort4 b;
        b.x = f2bf(v.x); b.y = f2bf(v.y); b.z = f2bf(v.z); b.w = f2bf(v.w);
        *(ushort4*)&lds[r * 136 + (c4 << 2)] = b;
    }
#pragma unroll
    for (int it = 0; it < 8; it++) {
        int i = it * 256 + tid;
        int r = i >> 5, c4 = i & 31;
        float4 v = *(const float4*)&W[r * 128 + (c4 << 2)];
        ushort4 b;
        b.x = f2bf(v.x); b.y = f2bf(v.y); b.z = f2bf(v.z); b.w = f2bf(v.w);
        *(ushort4*)&lds[(64 + r) * 136 + (c4 << 2)] = b;
    }
    __syncthreads();

    const int wv = tid >> 6;
    const int lane = tid & 63;
    const int q = lane >> 4;
    const int c = lane & 15;

    f32x4 acc[4];
#pragma unroll
    for (int t = 0; t < 4; t++) acc[t] = (f32x4){0.f, 0.f, 0.f, 0.f};

    const unsigned short* xrow = &lds[(wv * 16 + c) * 136];
    const unsigned short* wrow = &lds[(64 + c) * 136];

#pragma unroll
    for (int kk = 0; kk < 4; kk++) {
        int ko = kk * 32 + q * 8;
        bf16x8 a = *(const bf16x8*)&xrow[ko];
#pragma unroll
        for (int t = 0; t < 4; t++) {
            bf16x8 b = *(const bf16x8*)&wrow[t * 16 * 136 + ko];
            acc[t] = __builtin_amdgcn_mfma_f32_16x16x32_bf16(a, b, acc[t], 0, 0, 0);
        }
    }

#pragma unroll
    for (int r = 0; r < 4; r++) {
        int m = n0 + wv * 16 + q * 4 + r;
        if (m < NN) {
#pragma unroll
            for (int t = 0; t < 4; t++)
                h_bf[(size_t)m * OC + t * 16 + c] = f2bf(acc[t][r]);
        }
    }

    float al[4], ar[4];
#pragma unroll
    for (int t = 0; t < 4; t++) { al[t] = a_l[t * 16 + c]; ar[t] = a_r[t * 16 + c]; }
    float pl[4], pr[4];
#pragma unroll
    for (int r = 0; r < 4; r++) {
        pl[r] = al[0] * acc[0][r] + al[1] * acc[1][r] + al[2] * acc[2][r] + al[3] * acc[3][r];
        pr[r] = ar[0] * acc[0][r] + ar[1] * acc[1][r] + ar[2] * acc[2][r] + ar[3] * acc[3][r];
    }
#pragma unroll
    for (int m = 1; m < 16; m <<= 1) {
#pragma unroll
        for (int r = 0; r < 4; r++) {
            pl[r] += __shfl_xor(pl[r], m);
            pr[r] += __shfl_xor(pr[r], m);
        }
    }
    if (c == 0) {
#pragma unroll
        for (int r = 0; r < 4; r++) {
            int m = n0 + wv * 16 + q * 4 + r;
            if (m < NN) { e_l[m] = pl[r]; e_r[m] = pr[r]; }
        }
    }
}

// ---------------- K1: per-block LDS histogram over dst slices ----------------
__global__ __launch_bounds__(256) void hist_kernel(
    const int* __restrict__ dst, int* __restrict__ H)
{
    __shared__ int hist[NSLICE];
    const int t = threadIdx.x, b = blockIdx.x;
    if (t < NSLICE) hist[t] = 0;
    __syncthreads();
    for (int qi = t; qi < QPB; qi += 256) {
        int4 d = ((const int4*)dst)[b * QPB + qi];
        atomicAdd(&hist[d.x / SN], 1);
        atomicAdd(&hist[d.y / SN], 1);
        atomicAdd(&hist[d.z / SN], 1);
        atomicAdd(&hist[d.w / SN], 1);
    }
    __syncthreads();
    if (t < NSLICE) H[t * EB + b] = hist[t];   // slice-major, block-minor
}

// ---------------- K2: scan over H (length NN); bsums add folded into consumers ----------------
__global__ __launch_bounds__(1024) void scan_block_kernel(
    const int* __restrict__ deg, int* __restrict__ offsets,
    int* __restrict__ bsums)
{
    __shared__ int wsum[16];
    const int t = threadIdx.x;
    const int lane = t & 63, wv = t >> 6;
    const int i = blockIdx.x * 1024 + t;
    int v = (i < NN) ? deg[i] : 0;
    int incl = v;
#pragma unroll
    for (int off = 1; off < 64; off <<= 1) {
        int u = __shfl_up(incl, off);
        if (lane >= off) incl += u;
    }
    if (lane == 63) wsum[wv] = incl;
    __syncthreads();
    if (wv == 0 && lane < 16) {
        int s = wsum[lane];
        int si = s;
#pragma unroll
        for (int off = 1; off < 16; off <<= 1) {
            int u = __shfl_up(si, off);
            if (lane >= off) si += u;
        }
        wsum[lane] = si - s;
    }
    __syncthreads();
    int excl = incl - v + wsum[wv];
    if (i < NN) offsets[i] = excl;   // block-local exclusive
    if (t == 1023) bsums[blockIdx.x] = excl + v;
}

__global__ __launch_bounds__(128) void scan_bsums_kernel(int* __restrict__ bsums)
{
    __shared__ int s[128];
    const int t = threadIdx.x;
    const int NB = (NN + 1023) / 1024;
    int v = (t < NB) ? bsums[t] : 0;
    s[t] = v;
    __syncthreads();
    for (int off = 1; off < 128; off <<= 1) {
        int u = (t >= off) ? s[t - off] : 0;
        __syncthreads();
        s[t] += u;
        __syncthreads();
    }
    if (t < NB) bsums[t] = s[t] - v;   // exclusive block offsets
}

// ---------------- K3: bucket edges by slice (LDS cursors, packed 4B payload) ----------------
__global__ __launch_bounds__(256) void bucket_kernel(
    const int* __restrict__ src, const int* __restrict__ dst,
    const int* __restrict__ O_raw, const int* __restrict__ bsums,
    int* __restrict__ bucketed)
{
    __shared__ int cur[NSLICE];
    const int t = threadIdx.x, b = blockIdx.x;
    if (t < NSLICE) {
        int gi = t * EB + b;
        cur[t] = O_raw[gi] + bsums[gi >> 10];
    }
    __syncthreads();
    for (int qi = t; qi < QPB; qi += 256) {
        int4 d4 = ((const int4*)dst)[b * QPB + qi];
        int4 s4 = ((const int4*)src)[b * QPB + qi];
        int dd[4] = {d4.x, d4.y, d4.z, d4.w};
        int ss[4] = {s4.x, s4.y, s4.z, s4.w};
#pragma unroll
        for (int k = 0; k < 4; k++) {
            int sl = dd[k] / SN;
            int pos = atomicAdd(&cur[sl], 1);
            bucketed[pos] = ((dd[k] - sl * SN) << 17) | ss[k];   // dloc<512, src<2^17
        }
    }
}

// ---------------- K4: per-slice fine sort + softmax weights (pre-normalized) ----------------
__global__ __launch_bounds__(1024) void fine_sort_kernel(
    const int* __restrict__ bucketed, const int* __restrict__ O_raw,
    const int* __restrict__ bsums, const float* __restrict__ e_l,
    const float* __restrict__ e_r, float2* __restrict__ sorted_sw,
    int* __restrict__ offsets_out)
{
    __shared__ int ebuf[CAP];
    __shared__ float wbuf[CAP];
    __shared__ int hist[SN];
    __shared__ float nsum[SN];
    __shared__ float el[SN];
    __shared__ int wsums[8];
    const int s = blockIdx.x, t = threadIdx.x;
    int gi0 = s * EB;
    const int B0 = O_raw[gi0] + bsums[gi0 >> 10];
    int B1 = NE;
    if (s < NSLICE - 1) {
        int gi1 = (s + 1) * EB;
        B1 = O_raw[gi1] + bsums[gi1 >> 10];
    }
    int cnt = B1 - B0;
    if (cnt > CAP) cnt = CAP;              // statistically unreachable

    for (int i = t; i < cnt; i += 1024) ebuf[i] = bucketed[B0 + i];
    if (t < SN) {
        hist[t] = 0;
        nsum[t] = 0.f;
        el[t] = e_l[s * SN + t];
    }
    __syncthreads();
    // pass A: per-edge weight + per-node degree and weight-sum
    for (int i = t; i < cnt; i += 1024) {
        int p = ebuf[i];
        int dloc = p >> 17;
        int sr = p & 0x1FFFF;
        float a = el[dloc] + e_r[sr];
        a = (a > 0.f) ? a : NEG_SLOPE * a;
        float w = __expf(a);               // |a| small: fp32-safe, no max shift
        wbuf[i] = w;
        atomicAdd(&hist[dloc], 1);
        atomicAdd(&nsum[dloc], w);
    }
    __syncthreads();

    // exclusive scan of hist[0..SN) using waves 0..7
    const int lane = t & 63, w8 = t >> 6;
    int v = (t < SN) ? hist[t] : 0;
    int incl = v;
#pragma unroll
    for (int o = 1; o < 64; o <<= 1) {
        int u = __shfl_up(incl, o);
        if (lane >= o) incl += u;
    }
    if (w8 < 8 && lane == 63) wsums[w8] = incl;
    __syncthreads();
    if (t == 0) {
        int run = 0;
#pragma unroll
        for (int k = 0; k < 8; k++) { int x = wsums[k]; wsums[k] = run; run += x; }
    }
    __syncthreads();
    int excl = incl - v + ((w8 < 8) ? wsums[w8] : 0);

    if (t < SN) offsets_out[s * SN + t] = B0 + excl;
    __syncthreads();
    if (t < SN) hist[t] = excl;            // reuse as cursor
    __syncthreads();
    // pass B: place {src, w/(sum+eps)} into dense window
    for (int i = t; i < cnt; i += 1024) {
        int p = ebuf[i];
        int dloc = p >> 17;
        int pos = atomicAdd(&hist[dloc], 1);
        float wn = wbuf[i] / (nsum[dloc] + EPS_F);
        sorted_sw[B0 + pos] = make_float2(__int_as_float(p & 0x1FFFF), wn);
    }
    if (s == 0 && t == 0) offsets_out[NN] = NE;
}

// ---------------- aggregate: pure weighted gather-sum ----------------
// one wave per dst node; 8 lanes per edge, each lane gathers 16B (8 bf16 ch).
__global__ __launch_bounds__(256) void aggregate_kernel(
    const unsigned short* __restrict__ h_bf, const int* __restrict__ offsets,
    const float2* __restrict__ sorted_sw, const float* __restrict__ bias,
    float* __restrict__ out)
{
    const int node = blockIdx.x * 4 + (threadIdx.x >> 6);
    const int lane = threadIdx.x & 63;
    if (node >= NN) return;
    const int start = offsets[node];
    const int end = offsets[node + 1];
    const int grp = lane >> 3;
    const int ch = (lane & 7) * 8;

    float acc[8] = {0.f, 0.f, 0.f, 0.f, 0.f, 0.f, 0.f, 0.f};

#pragma unroll 2
    for (int j = start; j < end; j += 8) {
        int eidx = j + grp;
        int ej = (eidx < end) ? eidx : end - 1;
        float2 p = sorted_sw[ej];
        float w = (eidx < end) ? p.y : 0.f;     // weights pre-normalized
        int s = __float_as_int(p.x);
        uint4 qv = *(const uint4*)&h_bf[(size_t)s * OC + ch];
        acc[0] += w * __uint_as_float(qv.x << 16);
        acc[1] += w * __uint_as_float(qv.x & 0xffff0000u);
        acc[2] += w * __uint_as_float(qv.y << 16);
        acc[3] += w * __uint_as_float(qv.y & 0xffff0000u);
        acc[4] += w * __uint_as_float(qv.z << 16);
        acc[5] += w * __uint_as_float(qv.z & 0xffff0000u);
        acc[6] += w * __uint_as_float(qv.w << 16);
        acc[7] += w * __uint_as_float(qv.w & 0xffff0000u);
    }

#pragma unroll
    for (int m = 8; m <= 32; m <<= 1) {
#pragma unroll
        for (int k = 0; k < 8; k++) acc[k] += __shfl_xor(acc[k], m);
    }

    if (lane < 8) {
        float4 b0 = *(const float4*)&bias[lane * 8];
        float4 b1 = *(const float4*)&bias[lane * 8 + 4];
        float4 o0 = make_float4(acc[0] + b0.x, acc[1] + b0.y,
                                acc[2] + b0.z, acc[3] + b0.w);
        float4 o1 = make_float4(acc[4] + b1.x, acc[5] + b1.y,
                                acc[6] + b1.z, acc[7] + b1.w);
        *(float4*)&out[(size_t)node * OC + lane * 8] = o0;
        *(float4*)&out[(size_t)node * OC + lane * 8 + 4] = o1;
    }
}

extern "C" void kernel_launch(void* const* d_in, const int* in_sizes, int n_in,
                              void* d_out, int out_size, void* d_ws, size_t ws_size,
                              hipStream_t stream)
{
    const float* x = (const float*)d_in[0];
    const int* edge_index = (const int*)d_in[1];
    const float* W = (const float*)d_in[2];
    const float* a_l = (const float*)d_in[3];
    const float* a_r = (const float*)d_in[4];
    const float* bias = (const float*)d_in[5];
    float* out = (float*)d_out;

    const int* src = edge_index;       // row 0
    const int* dst = edge_index + NE;  // row 1

    // workspace layout (16B-aligned chunks); everything fully overwritten each call
    char* w = (char*)d_ws;
    unsigned short* h_bf = (unsigned short*)w;          // 12.8 MB
    size_t off = (size_t)NN * OC * 2;
    float* e_l = (float*)(w + off); off += (size_t)NN * 4;
    float* e_r = (float*)(w + off); off += (size_t)NN * 4;
    int* H = (int*)(w + off);       off += (size_t)NN * 4;          // NSLICE*EB == NN
    int* O_raw = (int*)(w + off);   off += (size_t)(NN + 4) * 4;
    int* bsums = (int*)(w + off);   off += 128 * 4;
    int* offsets = (int*)(w + off); off += (size_t)(NN + 4) * 4;
    int* bucketed = (int*)(w + off); off += (size_t)NE * 4;
    float2* sorted_sw = (float2*)(w + off); off += (size_t)NE * 8;

    linear_kernel<<<(NN + 63) / 64, 256, 0, stream>>>(x, W, a_l, a_r, h_bf, e_l, e_r);
    hist_kernel<<<EB, 256, 0, stream>>>(dst, H);
    scan_block_kernel<<<(NN + 1023) / 1024, 1024, 0, stream>>>(H, O_raw, bsums);
    scan_bsums_kernel<<<1, 128, 0, stream>>>(bsums);
    bucket_kernel<<<EB, 256, 0, stream>>>(src, dst, O_raw, bsums, bucketed);
    fine_sort_kernel<<<NSLICE, 1024, 0, stream>>>(bucketed, O_raw, bsums, e_l, e_r,
                                                  sorted_sw, offsets);
    aggregate_kernel<<<(NN + 3) / 4, 256, 0, stream>>>(h_bf, offsets, sorted_sw, bias, out);
}